// Round 2
// baseline (44799.203 us; speedup 1.0000x reference)
//
#include <hip/hip_runtime.h>
#include <stdint.h>
#include <stddef.h>

// ---------------------------------------------------------------------------
// GRBM Gibbs sampling, round 2: same exact JAX threefry numerics, faster fp32
// GEMMs. B=4096, V=3072, H=512, NUM_STEPS=8.
//  - logit kernel: 128x64 tile, 8x4 micro, grid=256 (1 blk/CU), XCD swizzle
//  - v-sample kernel: 128x128 tile, 8x8 micro, grid=768, double-buffered LDS
// Per-output accumulation remains ONE fmaf chain over ascending k -> results
// are bit-identical to round 1 (absmax should stay 0.1015625).
// ---------------------------------------------------------------------------

#define KT 16

__host__ __device__ inline void threefry2x32(uint32_t k0, uint32_t k1,
                                             uint32_t x0, uint32_t x1,
                                             uint32_t& o0, uint32_t& o1) {
  uint32_t ks2 = k0 ^ k1 ^ 0x1BD11BDAu;
  x0 += k0; x1 += k1;
#define TFR(r) { x0 += x1; x1 = (x1 << (r)) | (x1 >> (32 - (r))); x1 ^= x0; }
  TFR(13) TFR(15) TFR(26) TFR(6)
  x0 += k1;  x1 += ks2 + 1u;
  TFR(17) TFR(29) TFR(16) TFR(24)
  x0 += ks2; x1 += k0 + 2u;
  TFR(13) TFR(15) TFR(26) TFR(6)
  x0 += k0;  x1 += k1 + 3u;
  TFR(17) TFR(29) TFR(16) TFR(24)
  x0 += k1;  x1 += ks2 + 4u;
  TFR(13) TFR(15) TFR(26) TFR(6)
  x0 += ks2; x1 += k0 + 5u;
#undef TFR
  o0 = x0; o1 = x1;
}

__device__ inline uint32_t jax_bits32(uint32_t key0, uint32_t key1, uint32_t idx) {
  uint32_t o0, o1;
  threefry2x32(key0, key1, 0u, idx, o0, o1);
  return o0 ^ o1;
}

__device__ inline float jax_uniform01(uint32_t key0, uint32_t key1, uint32_t idx) {
  uint32_t bits = jax_bits32(key0, key1, idx);
  return __uint_as_float((bits >> 9) | 0x3f800000u) - 1.0f;
}

__device__ inline float erfinv_xla(float x) {
  float w = -log1pf(-x * x);
  float p;
  if (w < 5.0f) {
    w = w - 2.5f;
    p = 2.81022636e-08f;
    p = fmaf(p, w, 3.43273939e-07f);
    p = fmaf(p, w, -3.5233877e-06f);
    p = fmaf(p, w, -4.39150654e-06f);
    p = fmaf(p, w, 0.00021858087f);
    p = fmaf(p, w, -0.00125372503f);
    p = fmaf(p, w, -0.00417768164f);
    p = fmaf(p, w, 0.246640727f);
    p = fmaf(p, w, 1.50140941f);
  } else {
    w = sqrtf(w) - 3.0f;
    p = -0.000200214257f;
    p = fmaf(p, w, 0.000100950558f);
    p = fmaf(p, w, 0.00134934322f);
    p = fmaf(p, w, -0.00367342844f);
    p = fmaf(p, w, 0.00573950773f);
    p = fmaf(p, w, -0.0076224613f);
    p = fmaf(p, w, 0.00943887047f);
    p = fmaf(p, w, 1.00167406f);
    p = fmaf(p, w, 2.83297682f);
  }
  return p * x;
}

__global__ void prep_kernel(const float* __restrict__ log_var,
                            float* __restrict__ invvar,
                            float* __restrict__ stdv, int V) {
  int i = blockIdx.x * 256 + threadIdx.x;
  if (i < V) {
    float var = fmaxf(expf(log_var[i]), 1e-8f);
    invvar[i] = 1.0f / var;
    stdv[i] = sqrtf(var);
  }
}

// ---------------------------------------------------------------------------
// Kernel L: logits = (Vin*invvar) @ W + b ; h = bernoulli(sigmoid(logits))
// M=4096, N=512, K=3072. BM=128, BN=64, 256 thr, micro 8(m)x4(n).
// grid = 256 blocks (1/CU). XCD swizzle: 8 col-blocks of a row-panel -> 1 XCD.
// ---------------------------------------------------------------------------
__global__ __launch_bounds__(256)
void gemm_logit_bern(const float* __restrict__ Vin, const float* __restrict__ Wm,
                     const float* __restrict__ bias, const float* __restrict__ invvar,
                     uint8_t* __restrict__ Hout, uint32_t kb0, uint32_t kb1) {
  const int N = 512, K = 3072;
  __shared__ float As[2][KT][132];   // +4 pad: staging scatter-writes 2-way max
  __shared__ float Bs[2][KT][64];

  const int tid = threadIdx.x;
  // XCD-aware swizzle: bid -> (xcd = bid&7) gets 4 full row-panels x 8 col-blks
  const int bid = blockIdx.x;            // 0..255
  const int xcd = bid & 7;
  const int c = bid >> 3;                // 0..31
  const int mb = xcd * 4 + (c >> 3);     // 0..31
  const int nb = c & 7;                  // 0..7
  const int mBase = mb * 128, nBase = nb * 64;

  const int tx = tid & 15, ty = tid >> 4;     // n, m thread coords
  // A staging: slot s in {tid, tid+256}: m = s>>2 (0..127), k4 = (s&3)*4
  const int am = tid >> 2;                    // 0..63 ; +64 for second slot
  const int ak = (tid & 3) * 4;
  // B staging: k = tid>>4 (0..15), n = (tid&15)*4
  const int bk = tid >> 4;
  const int bn = (tid & 15) * 4;

  float acc[8][4] = {};

  float4 ra0, ra1, riv, rb;
  // prologue: chunk 0
  ra0 = *reinterpret_cast<const float4*>(&Vin[(size_t)(mBase + am) * K + ak]);
  ra1 = *reinterpret_cast<const float4*>(&Vin[(size_t)(mBase + am + 64) * K + ak]);
  riv = *reinterpret_cast<const float4*>(&invvar[ak]);
  rb  = *reinterpret_cast<const float4*>(&Wm[(size_t)bk * N + nBase + bn]);
  {
    float a0[4] = {ra0.x, ra0.y, ra0.z, ra0.w};
    float a1[4] = {ra1.x, ra1.y, ra1.z, ra1.w};
    float iv[4] = {riv.x, riv.y, riv.z, riv.w};
#pragma unroll
    for (int j = 0; j < 4; ++j) {
      As[0][ak + j][am]      = a0[j] * iv[j];
      As[0][ak + j][am + 64] = a1[j] * iv[j];
    }
    *reinterpret_cast<float4*>(&Bs[0][bk][bn]) = rb;
  }
  __syncthreads();

  int cur = 0;
  const int NT = K / KT;   // 192
  for (int t = 0; t < NT; ++t) {
    const bool more = (t + 1 < NT);
    if (more) {
      int k0 = (t + 1) * KT;
      ra0 = *reinterpret_cast<const float4*>(&Vin[(size_t)(mBase + am) * K + k0 + ak]);
      ra1 = *reinterpret_cast<const float4*>(&Vin[(size_t)(mBase + am + 64) * K + k0 + ak]);
      riv = *reinterpret_cast<const float4*>(&invvar[k0 + ak]);
      rb  = *reinterpret_cast<const float4*>(&Wm[(size_t)(k0 + bk) * N + nBase + bn]);
    }
#pragma unroll
    for (int kk = 0; kk < KT; ++kk) {
      float4 x0 = *reinterpret_cast<const float4*>(&As[cur][kk][ty * 8]);
      float4 x1 = *reinterpret_cast<const float4*>(&As[cur][kk][ty * 8 + 4]);
      float4 y  = *reinterpret_cast<const float4*>(&Bs[cur][kk][tx * 4]);
      float ar[8] = {x0.x, x0.y, x0.z, x0.w, x1.x, x1.y, x1.z, x1.w};
      float br[4] = {y.x, y.y, y.z, y.w};
#pragma unroll
      for (int i = 0; i < 8; ++i)
#pragma unroll
        for (int j = 0; j < 4; ++j)
          acc[i][j] = fmaf(ar[i], br[j], acc[i][j]);
    }
    if (more) {
      __syncthreads();
      float a0[4] = {ra0.x, ra0.y, ra0.z, ra0.w};
      float a1[4] = {ra1.x, ra1.y, ra1.z, ra1.w};
      float iv[4] = {riv.x, riv.y, riv.z, riv.w};
#pragma unroll
      for (int j = 0; j < 4; ++j) {
        As[cur ^ 1][ak + j][am]      = a0[j] * iv[j];
        As[cur ^ 1][ak + j][am + 64] = a1[j] * iv[j];
      }
      *reinterpret_cast<float4*>(&Bs[cur ^ 1][bk][bn]) = rb;
      __syncthreads();
      cur ^= 1;
    }
  }

#pragma unroll
  for (int i = 0; i < 8; ++i) {
    int row = mBase + ty * 8 + i;
    uchar4 h4;
    uint8_t* hb = &h4.x;
#pragma unroll
    for (int j = 0; j < 4; ++j) {
      int col = nBase + tx * 4 + j;
      float logit = acc[i][j] + bias[col];
      float p = 0.5f + 0.5f * tanhf(0.5f * logit);
      uint32_t idx = (uint32_t)row * (uint32_t)N + (uint32_t)col;
      float u = jax_uniform01(kb0, kb1, idx);
      hb[j] = (u < p) ? (uint8_t)1 : (uint8_t)0;
    }
    *reinterpret_cast<uchar4*>(&Hout[(size_t)row * N + nBase + tx * 4]) = h4;
  }
}

// ---------------------------------------------------------------------------
// Kernel V: v = h @ W^T + mu + normal*std.  M=4096, N=3072, K=512.
// BM=128, BN=128, 256 thr, micro 8x8 (B frag split tx*4 / 64+tx*4).
// grid = (24, 32) = 768 blocks.
// ---------------------------------------------------------------------------
__global__ __launch_bounds__(256)
void gemm_v_sample(const uint8_t* __restrict__ Hin, const float* __restrict__ Wm,
                   const float* __restrict__ muv, const float* __restrict__ stdv,
                   float* __restrict__ Vout, uint32_t kn0, uint32_t kn1) {
  const int N = 3072, K = 512;
  __shared__ float As[2][KT][132];
  __shared__ float Bs[2][KT][132];

  const int tid = threadIdx.x;
  const int mBase = blockIdx.y * 128, nBase = blockIdx.x * 128;
  const int tx = tid & 15, ty = tid >> 4;

  // A staging (h bytes): m = tid>>1 (0..127), kh = (tid&1)*8
  const int am = tid >> 1;
  const int ah = (tid & 1) * 8;
  // B staging: slot s in {tid, tid+256}: n = s>>2 (0..127), kq = (s&3)*4
  const int bn = tid >> 2;                 // 0..63 ; +64 for second slot
  const int bq = (tid & 3) * 4;

  float acc[8][8] = {};

  uint64_t rha;
  float4 rb0, rb1;
  rha = *reinterpret_cast<const uint64_t*>(&Hin[(size_t)(mBase + am) * K + ah]);
  rb0 = *reinterpret_cast<const float4*>(&Wm[(size_t)(nBase + bn) * K + bq]);
  rb1 = *reinterpret_cast<const float4*>(&Wm[(size_t)(nBase + bn + 64) * K + bq]);
  {
    float b0[4] = {rb0.x, rb0.y, rb0.z, rb0.w};
    float b1[4] = {rb1.x, rb1.y, rb1.z, rb1.w};
#pragma unroll
    for (int j = 0; j < 8; ++j)
      As[0][ah + j][am] = (float)((rha >> (8 * j)) & 0xffu);
#pragma unroll
    for (int j = 0; j < 4; ++j) {
      Bs[0][bq + j][bn]      = b0[j];
      Bs[0][bq + j][bn + 64] = b1[j];
    }
  }
  __syncthreads();

  int cur = 0;
  const int NT = K / KT;   // 32
  for (int t = 0; t < NT; ++t) {
    const bool more = (t + 1 < NT);
    if (more) {
      int k0 = (t + 1) * KT;
      rha = *reinterpret_cast<const uint64_t*>(&Hin[(size_t)(mBase + am) * K + k0 + ah]);
      rb0 = *reinterpret_cast<const float4*>(&Wm[(size_t)(nBase + bn) * K + k0 + bq]);
      rb1 = *reinterpret_cast<const float4*>(&Wm[(size_t)(nBase + bn + 64) * K + k0 + bq]);
    }
#pragma unroll
    for (int kk = 0; kk < KT; ++kk) {
      float4 x0 = *reinterpret_cast<const float4*>(&As[cur][kk][ty * 8]);
      float4 x1 = *reinterpret_cast<const float4*>(&As[cur][kk][ty * 8 + 4]);
      float4 y0 = *reinterpret_cast<const float4*>(&Bs[cur][kk][tx * 4]);
      float4 y1 = *reinterpret_cast<const float4*>(&Bs[cur][kk][64 + tx * 4]);
      float ar[8] = {x0.x, x0.y, x0.z, x0.w, x1.x, x1.y, x1.z, x1.w};
      float br[8] = {y0.x, y0.y, y0.z, y0.w, y1.x, y1.y, y1.z, y1.w};
#pragma unroll
      for (int i = 0; i < 8; ++i)
#pragma unroll
        for (int j = 0; j < 8; ++j)
          acc[i][j] = fmaf(ar[i], br[j], acc[i][j]);
    }
    if (more) {
      __syncthreads();
      float b0[4] = {rb0.x, rb0.y, rb0.z, rb0.w};
      float b1[4] = {rb1.x, rb1.y, rb1.z, rb1.w};
#pragma unroll
      for (int j = 0; j < 8; ++j)
        As[cur ^ 1][ah + j][am] = (float)((rha >> (8 * j)) & 0xffu);
#pragma unroll
      for (int j = 0; j < 4; ++j) {
        Bs[cur ^ 1][bq + j][bn]      = b0[j];
        Bs[cur ^ 1][bq + j][bn + 64] = b1[j];
      }
      __syncthreads();
      cur ^= 1;
    }
  }

  const float LO = -0.99999994f;
  const float SQRT2 = 1.41421356237f;
#pragma unroll
  for (int i = 0; i < 8; ++i) {
    int row = mBase + ty * 8 + i;
    float o[8];
#pragma unroll
    for (int j = 0; j < 8; ++j) {
      int col = nBase + ((j < 4) ? (tx * 4 + j) : (64 + tx * 4 + (j - 4)));
      float m_v = acc[i][j] + muv[col];
      uint32_t idx = (uint32_t)row * (uint32_t)N + (uint32_t)col;
      float f = jax_uniform01(kn0, kn1, idx);
      float u = fmaxf(LO, fmaf(f, 2.0f, LO));
      float nz = SQRT2 * erfinv_xla(u);
      o[j] = m_v + nz * stdv[col];
    }
    float4 s0 = {o[0], o[1], o[2], o[3]};
    float4 s1 = {o[4], o[5], o[6], o[7]};
    *reinterpret_cast<float4*>(&Vout[(size_t)row * N + nBase + tx * 4]) = s0;
    *reinterpret_cast<float4*>(&Vout[(size_t)row * N + nBase + 64 + tx * 4]) = s1;
  }
}

extern "C" void kernel_launch(void* const* d_in, const int* in_sizes, int n_in,
                              void* d_out, int out_size, void* d_ws, size_t ws_size,
                              hipStream_t stream) {
  const int B = 4096, V = 3072, NUM_STEPS = 8;
  const float* v_in    = (const float*)d_in[0];
  const float* W       = (const float*)d_in[1];
  const float* b       = (const float*)d_in[2];
  const float* mu      = (const float*)d_in[3];
  const float* log_var = (const float*)d_in[4];
  float* out = (float*)d_out;

  float* invvar = (float*)d_ws;
  float* stdv   = invvar + V;
  uint8_t* h    = (uint8_t*)(stdv + V);   // B*H = 2 MiB

  uint32_t k0a, k0b, kl0, kl1;
  threefry2x32(0u, 42u, 0u, 0u, k0a, k0b);
  threefry2x32(0u, 42u, 0u, 1u, kl0, kl1);
  uint32_t kn0[NUM_STEPS], kn1[NUM_STEPS], kb0[NUM_STEPS], kb1[NUM_STEPS];
  for (int t = 0; t < NUM_STEPS; ++t) {
    uint32_t kt0, kt1;
    threefry2x32(kl0, kl1, 0u, (uint32_t)t, kt0, kt1);
    threefry2x32(kt0, kt1, 0u, 0u, kn0[t], kn1[t]);
    threefry2x32(kt0, kt1, 0u, 1u, kb0[t], kb1[t]);
  }

  prep_kernel<<<(V + 255) / 256, 256, 0, stream>>>(log_var, invvar, stdv, V);

  dim3 gridL(256);          // (M/128)*(N/64) = 32*8
  dim3 gridV(V / 128, B / 128);   // (24, 32)

  gemm_logit_bern<<<gridL, 256, 0, stream>>>(v_in, W, b, invvar, h, k0a, k0b);

  for (int t = 0; t < NUM_STEPS; ++t) {
    float* vt = out + (size_t)t * B * V;
    gemm_v_sample<<<gridV, 256, 0, stream>>>(h, W, mu, stdv, vt, kn0[t], kn1[t]);
    if (t < NUM_STEPS - 1) {
      gemm_logit_bern<<<gridL, 256, 0, stream>>>(vt, W, b, invvar, h, kb0[t], kb1[t]);
    }
  }
}

// Round 3
// 6104.591 us; speedup vs baseline: 7.3386x; 7.3386x over previous
//
#include <hip/hip_runtime.h>
#include <stdint.h>
#include <stddef.h>

// ---------------------------------------------------------------------------
// GRBM Gibbs sampling, round 3. Same exact JAX threefry numerics (absmax must
// stay 0.1015625). Fixes round-2 register-spill catastrophe:
//   - __launch_bounds__(256, 1): full VGPR budget (R2: VGPR=56 -> acc spilled,
//     9.1 GB/dispatch scratch writes)
//   - microkernel FMAs via literal-index macros, no temp arrays
// Kernel V: 128x128, 8x8 micro, dbuf.  Kernel L: 64x64, 4x4 micro, dbuf,
// XCD-swizzled so a Vin row-panel's 8 col-blocks share one XCD's L2.
// ---------------------------------------------------------------------------

#define KT 16

__host__ __device__ inline void threefry2x32(uint32_t k0, uint32_t k1,
                                             uint32_t x0, uint32_t x1,
                                             uint32_t& o0, uint32_t& o1) {
  uint32_t ks2 = k0 ^ k1 ^ 0x1BD11BDAu;
  x0 += k0; x1 += k1;
#define TFR(r) { x0 += x1; x1 = (x1 << (r)) | (x1 >> (32 - (r))); x1 ^= x0; }
  TFR(13) TFR(15) TFR(26) TFR(6)
  x0 += k1;  x1 += ks2 + 1u;
  TFR(17) TFR(29) TFR(16) TFR(24)
  x0 += ks2; x1 += k0 + 2u;
  TFR(13) TFR(15) TFR(26) TFR(6)
  x0 += k0;  x1 += k1 + 3u;
  TFR(17) TFR(29) TFR(16) TFR(24)
  x0 += k1;  x1 += ks2 + 4u;
  TFR(13) TFR(15) TFR(26) TFR(6)
  x0 += ks2; x1 += k0 + 5u;
#undef TFR
  o0 = x0; o1 = x1;
}

__device__ inline float jax_uniform01(uint32_t key0, uint32_t key1, uint32_t idx) {
  uint32_t o0, o1;
  threefry2x32(key0, key1, 0u, idx, o0, o1);
  uint32_t bits = o0 ^ o1;
  return __uint_as_float((bits >> 9) | 0x3f800000u) - 1.0f;
}

__device__ inline float erfinv_xla(float x) {
  float w = -log1pf(-x * x);
  float p;
  if (w < 5.0f) {
    w = w - 2.5f;
    p = 2.81022636e-08f;
    p = fmaf(p, w, 3.43273939e-07f);
    p = fmaf(p, w, -3.5233877e-06f);
    p = fmaf(p, w, -4.39150654e-06f);
    p = fmaf(p, w, 0.00021858087f);
    p = fmaf(p, w, -0.00125372503f);
    p = fmaf(p, w, -0.00417768164f);
    p = fmaf(p, w, 0.246640727f);
    p = fmaf(p, w, 1.50140941f);
  } else {
    w = sqrtf(w) - 3.0f;
    p = -0.000200214257f;
    p = fmaf(p, w, 0.000100950558f);
    p = fmaf(p, w, 0.00134934322f);
    p = fmaf(p, w, -0.00367342844f);
    p = fmaf(p, w, 0.00573950773f);
    p = fmaf(p, w, -0.0076224613f);
    p = fmaf(p, w, 0.00943887047f);
    p = fmaf(p, w, 1.00167406f);
    p = fmaf(p, w, 2.83297682f);
  }
  return p * x;
}

__global__ void prep_kernel(const float* __restrict__ log_var,
                            float* __restrict__ invvar,
                            float* __restrict__ stdv, int V) {
  int i = blockIdx.x * 256 + threadIdx.x;
  if (i < V) {
    float var = fmaxf(expf(log_var[i]), 1e-8f);
    invvar[i] = 1.0f / var;
    stdv[i] = sqrtf(var);
  }
}

// ---------------------------------------------------------------------------
// Kernel L: logits = (Vin*invvar) @ W + b ; h = bernoulli(sigmoid(logits))
// M=4096, N=512, K=3072. BM=64, BN=64, 256 thr, micro 4x4, dbuf.
// grid=512; XCD swizzle: xcd = bid&7 owns row-panels [xcd*8, xcd*8+8) x all nb.
// ---------------------------------------------------------------------------
__global__ __launch_bounds__(256, 1)
void gemm_logit_bern(const float* __restrict__ Vin, const float* __restrict__ Wm,
                     const float* __restrict__ bias, const float* __restrict__ invvar,
                     uint8_t* __restrict__ Hout, uint32_t kb0, uint32_t kb1) {
  const int N = 512, K = 3072;
  __shared__ float As[2][KT][68];   // [k][m], +4 pad
  __shared__ float Bs[2][KT][64];   // [k][n]

  const int tid = threadIdx.x;
  const int bid = blockIdx.x;            // 0..511
  const int xcd = bid & 7;
  const int c = bid >> 3;                // 0..63
  const int mb = xcd * 8 + (c >> 3);     // 0..63
  const int nb = c & 7;                  // 0..7
  const int mBase = mb * 64, nBase = nb * 64;

  const int tx = tid & 15, ty = tid >> 4;
  const int am = tid >> 2;               // 0..63
  const int ak = (tid & 3) * 4;          // 0,4,8,12
  const int bk = tid >> 4;               // 0..15
  const int bn = (tid & 15) * 4;         // 0..60

  float acc[4][4] = {};

  float4 ra, riv, rb;
  ra  = *reinterpret_cast<const float4*>(&Vin[(size_t)(mBase + am) * K + ak]);
  riv = *reinterpret_cast<const float4*>(&invvar[ak]);
  rb  = *reinterpret_cast<const float4*>(&Wm[(size_t)bk * N + nBase + bn]);
  As[0][ak + 0][am] = ra.x * riv.x;
  As[0][ak + 1][am] = ra.y * riv.y;
  As[0][ak + 2][am] = ra.z * riv.z;
  As[0][ak + 3][am] = ra.w * riv.w;
  *reinterpret_cast<float4*>(&Bs[0][bk][bn]) = rb;
  __syncthreads();

  int cur = 0;
  const int NT = K / KT;   // 192
  for (int t = 0; t < NT; ++t) {
    const bool more = (t + 1 < NT);
    if (more) {
      int k0 = (t + 1) * KT;
      ra  = *reinterpret_cast<const float4*>(&Vin[(size_t)(mBase + am) * K + k0 + ak]);
      riv = *reinterpret_cast<const float4*>(&invvar[k0 + ak]);
      rb  = *reinterpret_cast<const float4*>(&Wm[(size_t)(k0 + bk) * N + nBase + bn]);
    }
#pragma unroll
    for (int kk = 0; kk < KT; ++kk) {
      float4 x = *reinterpret_cast<const float4*>(&As[cur][kk][ty * 4]);
      float4 y = *reinterpret_cast<const float4*>(&Bs[cur][kk][tx * 4]);
#define LROW(i, a) \
      acc[i][0] = fmaf(a, y.x, acc[i][0]); \
      acc[i][1] = fmaf(a, y.y, acc[i][1]); \
      acc[i][2] = fmaf(a, y.z, acc[i][2]); \
      acc[i][3] = fmaf(a, y.w, acc[i][3]);
      LROW(0, x.x) LROW(1, x.y) LROW(2, x.z) LROW(3, x.w)
#undef LROW
    }
    if (more) {
      __syncthreads();
      As[cur ^ 1][ak + 0][am] = ra.x * riv.x;
      As[cur ^ 1][ak + 1][am] = ra.y * riv.y;
      As[cur ^ 1][ak + 2][am] = ra.z * riv.z;
      As[cur ^ 1][ak + 3][am] = ra.w * riv.w;
      *reinterpret_cast<float4*>(&Bs[cur ^ 1][bk][bn]) = rb;
      __syncthreads();
      cur ^= 1;
    }
  }

#pragma unroll
  for (int i = 0; i < 4; ++i) {
    int row = mBase + ty * 4 + i;
    uchar4 h4;
    uint8_t* hb = &h4.x;
#pragma unroll
    for (int j = 0; j < 4; ++j) {
      int col = nBase + tx * 4 + j;
      float logit = acc[i][j] + bias[col];
      float p = 0.5f + 0.5f * tanhf(0.5f * logit);
      uint32_t idx = (uint32_t)row * (uint32_t)N + (uint32_t)col;
      float u = jax_uniform01(kb0, kb1, idx);
      hb[j] = (u < p) ? (uint8_t)1 : (uint8_t)0;
    }
    *reinterpret_cast<uchar4*>(&Hout[(size_t)row * N + nBase + tx * 4]) = h4;
  }
}

// ---------------------------------------------------------------------------
// Kernel V: v = h @ W^T + mu + normal*std.  M=4096, N=3072, K=512.
// BM=128, BN=128, 256 thr, micro 8x8, dbuf. grid = (24, 32).
// ---------------------------------------------------------------------------
__global__ __launch_bounds__(256, 1)
void gemm_v_sample(const uint8_t* __restrict__ Hin, const float* __restrict__ Wm,
                   const float* __restrict__ muv, const float* __restrict__ stdv,
                   float* __restrict__ Vout, uint32_t kn0, uint32_t kn1) {
  const int N = 3072, K = 512;
  __shared__ float As[2][KT][132];
  __shared__ float Bs[2][KT][132];

  const int tid = threadIdx.x;
  const int mBase = blockIdx.y * 128, nBase = blockIdx.x * 128;
  const int tx = tid & 15, ty = tid >> 4;

  const int am = tid >> 1;               // 0..127
  const int ah = (tid & 1) * 8;          // 0,8
  const int bn = tid >> 2;               // 0..63 ; +64 second slot
  const int bq = (tid & 3) * 4;          // 0,4,8,12

  float acc[8][8] = {};

  uint64_t rha;
  float4 rb0, rb1;
  rha = *reinterpret_cast<const uint64_t*>(&Hin[(size_t)(mBase + am) * K + ah]);
  rb0 = *reinterpret_cast<const float4*>(&Wm[(size_t)(nBase + bn) * K + bq]);
  rb1 = *reinterpret_cast<const float4*>(&Wm[(size_t)(nBase + bn + 64) * K + bq]);
#define STAGE_V(buf) { \
  As[buf][ah + 0][am] = (float)((rha >> 0) & 0xffu); \
  As[buf][ah + 1][am] = (float)((rha >> 8) & 0xffu); \
  As[buf][ah + 2][am] = (float)((rha >> 16) & 0xffu); \
  As[buf][ah + 3][am] = (float)((rha >> 24) & 0xffu); \
  As[buf][ah + 4][am] = (float)((rha >> 32) & 0xffu); \
  As[buf][ah + 5][am] = (float)((rha >> 40) & 0xffu); \
  As[buf][ah + 6][am] = (float)((rha >> 48) & 0xffu); \
  As[buf][ah + 7][am] = (float)((rha >> 56) & 0xffu); \
  Bs[buf][bq + 0][bn]      = rb0.x; \
  Bs[buf][bq + 1][bn]      = rb0.y; \
  Bs[buf][bq + 2][bn]      = rb0.z; \
  Bs[buf][bq + 3][bn]      = rb0.w; \
  Bs[buf][bq + 0][bn + 64] = rb1.x; \
  Bs[buf][bq + 1][bn + 64] = rb1.y; \
  Bs[buf][bq + 2][bn + 64] = rb1.z; \
  Bs[buf][bq + 3][bn + 64] = rb1.w; }

  STAGE_V(0)
  __syncthreads();

  int cur = 0;
  const int NT = K / KT;   // 32
  for (int t = 0; t < NT; ++t) {
    const bool more = (t + 1 < NT);
    if (more) {
      int k0 = (t + 1) * KT;
      rha = *reinterpret_cast<const uint64_t*>(&Hin[(size_t)(mBase + am) * K + k0 + ah]);
      rb0 = *reinterpret_cast<const float4*>(&Wm[(size_t)(nBase + bn) * K + k0 + bq]);
      rb1 = *reinterpret_cast<const float4*>(&Wm[(size_t)(nBase + bn + 64) * K + k0 + bq]);
    }
#pragma unroll
    for (int kk = 0; kk < KT; ++kk) {
      float4 x0 = *reinterpret_cast<const float4*>(&As[cur][kk][ty * 8]);
      float4 x1 = *reinterpret_cast<const float4*>(&As[cur][kk][ty * 8 + 4]);
      float4 y0 = *reinterpret_cast<const float4*>(&Bs[cur][kk][tx * 4]);
      float4 y1 = *reinterpret_cast<const float4*>(&Bs[cur][kk][64 + tx * 4]);
#define VROW(i, a) \
      acc[i][0] = fmaf(a, y0.x, acc[i][0]); \
      acc[i][1] = fmaf(a, y0.y, acc[i][1]); \
      acc[i][2] = fmaf(a, y0.z, acc[i][2]); \
      acc[i][3] = fmaf(a, y0.w, acc[i][3]); \
      acc[i][4] = fmaf(a, y1.x, acc[i][4]); \
      acc[i][5] = fmaf(a, y1.y, acc[i][5]); \
      acc[i][6] = fmaf(a, y1.z, acc[i][6]); \
      acc[i][7] = fmaf(a, y1.w, acc[i][7]);
      VROW(0, x0.x) VROW(1, x0.y) VROW(2, x0.z) VROW(3, x0.w)
      VROW(4, x1.x) VROW(5, x1.y) VROW(6, x1.z) VROW(7, x1.w)
#undef VROW
    }
    if (more) {
      __syncthreads();
      STAGE_V(cur ^ 1)
      __syncthreads();
      cur ^= 1;
    }
  }
#undef STAGE_V

  const float LO = -0.99999994f;
  const float SQRT2 = 1.41421356237f;
#pragma unroll
  for (int i = 0; i < 8; ++i) {
    int row = mBase + ty * 8 + i;
    float o[8];
#pragma unroll
    for (int j = 0; j < 8; ++j) {
      int col = nBase + ((j < 4) ? (tx * 4 + j) : (64 + tx * 4 + (j - 4)));
      float m_v = acc[i][j] + muv[col];
      uint32_t idx = (uint32_t)row * (uint32_t)N + (uint32_t)col;
      float f = jax_uniform01(kn0, kn1, idx);
      float u = fmaxf(LO, fmaf(f, 2.0f, LO));
      float nz = SQRT2 * erfinv_xla(u);
      o[j] = m_v + nz * stdv[col];
    }
    float4 s0 = {o[0], o[1], o[2], o[3]};
    float4 s1 = {o[4], o[5], o[6], o[7]};
    *reinterpret_cast<float4*>(&Vout[(size_t)row * N + nBase + tx * 4]) = s0;
    *reinterpret_cast<float4*>(&Vout[(size_t)row * N + nBase + 64 + tx * 4]) = s1;
  }
}

extern "C" void kernel_launch(void* const* d_in, const int* in_sizes, int n_in,
                              void* d_out, int out_size, void* d_ws, size_t ws_size,
                              hipStream_t stream) {
  const int B = 4096, V = 3072, NUM_STEPS = 8;
  const float* v_in    = (const float*)d_in[0];
  const float* W       = (const float*)d_in[1];
  const float* b       = (const float*)d_in[2];
  const float* mu      = (const float*)d_in[3];
  const float* log_var = (const float*)d_in[4];
  float* out = (float*)d_out;

  float* invvar = (float*)d_ws;
  float* stdv   = invvar + V;
  uint8_t* h    = (uint8_t*)(stdv + V);   // B*H = 2 MiB

  uint32_t k0a, k0b, kl0, kl1;
  threefry2x32(0u, 42u, 0u, 0u, k0a, k0b);
  threefry2x32(0u, 42u, 0u, 1u, kl0, kl1);
  uint32_t kn0[NUM_STEPS], kn1[NUM_STEPS], kb0[NUM_STEPS], kb1[NUM_STEPS];
  for (int t = 0; t < NUM_STEPS; ++t) {
    uint32_t kt0, kt1;
    threefry2x32(kl0, kl1, 0u, (uint32_t)t, kt0, kt1);
    threefry2x32(kt0, kt1, 0u, 0u, kn0[t], kn1[t]);
    threefry2x32(kt0, kt1, 0u, 1u, kb0[t], kb1[t]);
  }

  prep_kernel<<<(V + 255) / 256, 256, 0, stream>>>(log_var, invvar, stdv, V);

  dim3 gridL(512);                 // (M/64)*(N/64) = 64*8, XCD-swizzled
  dim3 gridV(V / 128, B / 128);    // (24, 32)

  gemm_logit_bern<<<gridL, 256, 0, stream>>>(v_in, W, b, invvar, h, k0a, k0b);

  for (int t = 0; t < NUM_STEPS; ++t) {
    float* vt = out + (size_t)t * B * V;
    gemm_v_sample<<<gridV, 256, 0, stream>>>(h, W, mu, stdv, vt, kn0[t], kn1[t]);
    if (t < NUM_STEPS - 1) {
      gemm_logit_bern<<<gridL, 256, 0, stream>>>(vt, W, b, invvar, h, kb0[t], kb1[t]);
    }
  }
}

// Round 4
// 3496.848 us; speedup vs baseline: 12.8113x; 1.7457x over previous
//
#include <hip/hip_runtime.h>
#include <stdint.h>
#include <stddef.h>

// ---------------------------------------------------------------------------
// GRBM Gibbs sampling, round 4. Exact JAX threefry numerics (absmax must stay
// 0.1015625 — every output keeps ONE ascending-k fmaf chain).
// R3 post-mortem: V @128x128/8x8/33KB-dbuf hit phantom 1 GiB/dispatch HBM
// writes (scratch signature) + occupancy collapse. Rebuild V on the proven
// 128x64/8x4 dbuf template (R3-L lineage). L unchanged except removing an
// address-taken local (uchar4 pack via uint32).
// ---------------------------------------------------------------------------

#define KT 16

__host__ __device__ inline void threefry2x32(uint32_t k0, uint32_t k1,
                                             uint32_t x0, uint32_t x1,
                                             uint32_t& o0, uint32_t& o1) {
  uint32_t ks2 = k0 ^ k1 ^ 0x1BD11BDAu;
  x0 += k0; x1 += k1;
#define TFR(r) { x0 += x1; x1 = (x1 << (r)) | (x1 >> (32 - (r))); x1 ^= x0; }
  TFR(13) TFR(15) TFR(26) TFR(6)
  x0 += k1;  x1 += ks2 + 1u;
  TFR(17) TFR(29) TFR(16) TFR(24)
  x0 += ks2; x1 += k0 + 2u;
  TFR(13) TFR(15) TFR(26) TFR(6)
  x0 += k0;  x1 += k1 + 3u;
  TFR(17) TFR(29) TFR(16) TFR(24)
  x0 += k1;  x1 += ks2 + 4u;
  TFR(13) TFR(15) TFR(26) TFR(6)
  x0 += ks2; x1 += k0 + 5u;
#undef TFR
  o0 = x0; o1 = x1;
}

__device__ inline float jax_uniform01(uint32_t key0, uint32_t key1, uint32_t idx) {
  uint32_t o0, o1;
  threefry2x32(key0, key1, 0u, idx, o0, o1);
  uint32_t bits = o0 ^ o1;
  return __uint_as_float((bits >> 9) | 0x3f800000u) - 1.0f;
}

__device__ inline float erfinv_xla(float x) {
  float w = -log1pf(-x * x);
  float p;
  if (w < 5.0f) {
    w = w - 2.5f;
    p = 2.81022636e-08f;
    p = fmaf(p, w, 3.43273939e-07f);
    p = fmaf(p, w, -3.5233877e-06f);
    p = fmaf(p, w, -4.39150654e-06f);
    p = fmaf(p, w, 0.00021858087f);
    p = fmaf(p, w, -0.00125372503f);
    p = fmaf(p, w, -0.00417768164f);
    p = fmaf(p, w, 0.246640727f);
    p = fmaf(p, w, 1.50140941f);
  } else {
    w = sqrtf(w) - 3.0f;
    p = -0.000200214257f;
    p = fmaf(p, w, 0.000100950558f);
    p = fmaf(p, w, 0.00134934322f);
    p = fmaf(p, w, -0.00367342844f);
    p = fmaf(p, w, 0.00573950773f);
    p = fmaf(p, w, -0.0076224613f);
    p = fmaf(p, w, 0.00943887047f);
    p = fmaf(p, w, 1.00167406f);
    p = fmaf(p, w, 2.83297682f);
  }
  return p * x;
}

__global__ void prep_kernel(const float* __restrict__ log_var,
                            float* __restrict__ invvar,
                            float* __restrict__ stdv, int V) {
  int i = blockIdx.x * 256 + threadIdx.x;
  if (i < V) {
    float var = fmaxf(expf(log_var[i]), 1e-8f);
    invvar[i] = 1.0f / var;
    stdv[i] = sqrtf(var);
  }
}

// ---------------------------------------------------------------------------
// Kernel L: logits = (Vin*invvar) @ W + b ; h = bernoulli(sigmoid(logits))
// M=4096, N=512, K=3072. BM=64, BN=64, 256 thr, micro 4x4, dbuf.
// grid=512; XCD swizzle: xcd = bid&7 owns row-panels [xcd*8, xcd*8+8).
// ---------------------------------------------------------------------------
__global__ __launch_bounds__(256, 1)
void gemm_logit_bern(const float* __restrict__ Vin, const float* __restrict__ Wm,
                     const float* __restrict__ bias, const float* __restrict__ invvar,
                     uint8_t* __restrict__ Hout, uint32_t kb0, uint32_t kb1) {
  const int N = 512, K = 3072;
  __shared__ float As[2][KT][68];
  __shared__ float Bs[2][KT][64];

  const int tid = threadIdx.x;
  const int bid = blockIdx.x;
  const int xcd = bid & 7;
  const int c = bid >> 3;
  const int mb = xcd * 8 + (c >> 3);
  const int nb = c & 7;
  const int mBase = mb * 64, nBase = nb * 64;

  const int tx = tid & 15, ty = tid >> 4;
  const int am = tid >> 2;
  const int ak = (tid & 3) * 4;
  const int bk = tid >> 4;
  const int bn = (tid & 15) * 4;

  float acc[4][4] = {};

  float4 ra, riv, rb;
  ra  = *reinterpret_cast<const float4*>(&Vin[(size_t)(mBase + am) * K + ak]);
  riv = *reinterpret_cast<const float4*>(&invvar[ak]);
  rb  = *reinterpret_cast<const float4*>(&Wm[(size_t)bk * N + nBase + bn]);
  As[0][ak + 0][am] = ra.x * riv.x;
  As[0][ak + 1][am] = ra.y * riv.y;
  As[0][ak + 2][am] = ra.z * riv.z;
  As[0][ak + 3][am] = ra.w * riv.w;
  *reinterpret_cast<float4*>(&Bs[0][bk][bn]) = rb;
  __syncthreads();

  int cur = 0;
  const int NT = K / KT;   // 192
  for (int t = 0; t < NT; ++t) {
    const bool more = (t + 1 < NT);
    if (more) {
      int k0 = (t + 1) * KT;
      ra  = *reinterpret_cast<const float4*>(&Vin[(size_t)(mBase + am) * K + k0 + ak]);
      riv = *reinterpret_cast<const float4*>(&invvar[k0 + ak]);
      rb  = *reinterpret_cast<const float4*>(&Wm[(size_t)(k0 + bk) * N + nBase + bn]);
    }
#pragma unroll
    for (int kk = 0; kk < KT; ++kk) {
      float4 x = *reinterpret_cast<const float4*>(&As[cur][kk][ty * 4]);
      float4 y = *reinterpret_cast<const float4*>(&Bs[cur][kk][tx * 4]);
#define LROW(i, a) \
      acc[i][0] = fmaf(a, y.x, acc[i][0]); \
      acc[i][1] = fmaf(a, y.y, acc[i][1]); \
      acc[i][2] = fmaf(a, y.z, acc[i][2]); \
      acc[i][3] = fmaf(a, y.w, acc[i][3]);
      LROW(0, x.x) LROW(1, x.y) LROW(2, x.z) LROW(3, x.w)
#undef LROW
    }
    if (more) {
      __syncthreads();
      As[cur ^ 1][ak + 0][am] = ra.x * riv.x;
      As[cur ^ 1][ak + 1][am] = ra.y * riv.y;
      As[cur ^ 1][ak + 2][am] = ra.z * riv.z;
      As[cur ^ 1][ak + 3][am] = ra.w * riv.w;
      *reinterpret_cast<float4*>(&Bs[cur ^ 1][bk][bn]) = rb;
      __syncthreads();
      cur ^= 1;
    }
  }

#pragma unroll
  for (int i = 0; i < 4; ++i) {
    int row = mBase + ty * 4 + i;
    uint32_t hp = 0;
#pragma unroll
    for (int j = 0; j < 4; ++j) {
      int col = nBase + tx * 4 + j;
      float logit = acc[i][j] + bias[col];
      float p = 0.5f + 0.5f * tanhf(0.5f * logit);
      uint32_t idx = (uint32_t)row * (uint32_t)N + (uint32_t)col;
      float u = jax_uniform01(kb0, kb1, idx);
      hp |= ((u < p) ? 1u : 0u) << (8 * j);
    }
    *reinterpret_cast<uint32_t*>(&Hout[(size_t)row * N + nBase + tx * 4]) = hp;
  }
}

// ---------------------------------------------------------------------------
// Kernel V: v = h @ W^T + mu + normal*std.  M=4096, N=3072, K=512.
// BM=128, BN=64, 256 thr, micro 8(m)x4(n), dbuf. grid = (48, 32).
// LDS 25.6 KB -> 6 blocks/CU. VGPR target ~90 (cap 256 via bounds(256,2)).
// ---------------------------------------------------------------------------
__global__ __launch_bounds__(256, 2)
void gemm_v_sample(const uint8_t* __restrict__ Hin, const float* __restrict__ Wm,
                   const float* __restrict__ muv, const float* __restrict__ stdv,
                   float* __restrict__ Vout, uint32_t kn0, uint32_t kn1) {
  const int N = 3072, K = 512;
  __shared__ float As[2][KT][132];   // [k][m 0..127]
  __shared__ float Bs[2][KT][68];    // [k][n 0..63]

  const int tid = threadIdx.x;
  const int mBase = blockIdx.y * 128, nBase = blockIdx.x * 64;
  const int tx = tid & 15, ty = tid >> 4;   // n(4 each), m(8 each)

  // A staging: h bytes, m = tid>>1 (0..127), ah = (tid&1)*8
  const int am = tid >> 1;
  const int ah = (tid & 1) * 8;
  // B staging: W rows (n), bn = tid>>2 (0..63), bq = (tid&3)*4
  const int bn = tid >> 2;
  const int bq = (tid & 3) * 4;

  float acc[8][4] = {};

  uint32_t rh0, rh1;
  float4 rb;
  {
    const uint32_t* hp = reinterpret_cast<const uint32_t*>(&Hin[(size_t)(mBase + am) * K + ah]);
    rh0 = hp[0]; rh1 = hp[1];
  }
  rb = *reinterpret_cast<const float4*>(&Wm[(size_t)(nBase + bn) * K + bq]);

#define STAGE_V(buf) { \
  As[buf][ah + 0][am] = (float)((rh0 >> 0) & 0xffu); \
  As[buf][ah + 1][am] = (float)((rh0 >> 8) & 0xffu); \
  As[buf][ah + 2][am] = (float)((rh0 >> 16) & 0xffu); \
  As[buf][ah + 3][am] = (float)((rh0 >> 24) & 0xffu); \
  As[buf][ah + 4][am] = (float)((rh1 >> 0) & 0xffu); \
  As[buf][ah + 5][am] = (float)((rh1 >> 8) & 0xffu); \
  As[buf][ah + 6][am] = (float)((rh1 >> 16) & 0xffu); \
  As[buf][ah + 7][am] = (float)((rh1 >> 24) & 0xffu); \
  Bs[buf][bq + 0][bn] = rb.x; \
  Bs[buf][bq + 1][bn] = rb.y; \
  Bs[buf][bq + 2][bn] = rb.z; \
  Bs[buf][bq + 3][bn] = rb.w; }

  STAGE_V(0)
  __syncthreads();

  int cur = 0;
  const int NT = K / KT;   // 32
  for (int t = 0; t < NT; ++t) {
    const bool more = (t + 1 < NT);
    if (more) {
      int k0 = (t + 1) * KT;
      const uint32_t* hp = reinterpret_cast<const uint32_t*>(&Hin[(size_t)(mBase + am) * K + k0 + ah]);
      rh0 = hp[0]; rh1 = hp[1];
      rb = *reinterpret_cast<const float4*>(&Wm[(size_t)(nBase + bn) * K + k0 + bq]);
    }
#pragma unroll
    for (int kk = 0; kk < KT; ++kk) {
      float4 x0 = *reinterpret_cast<const float4*>(&As[cur][kk][ty * 8]);
      float4 x1 = *reinterpret_cast<const float4*>(&As[cur][kk][ty * 8 + 4]);
      float4 y  = *reinterpret_cast<const float4*>(&Bs[cur][kk][tx * 4]);
#define VROW(i, a) \
      acc[i][0] = fmaf(a, y.x, acc[i][0]); \
      acc[i][1] = fmaf(a, y.y, acc[i][1]); \
      acc[i][2] = fmaf(a, y.z, acc[i][2]); \
      acc[i][3] = fmaf(a, y.w, acc[i][3]);
      VROW(0, x0.x) VROW(1, x0.y) VROW(2, x0.z) VROW(3, x0.w)
      VROW(4, x1.x) VROW(5, x1.y) VROW(6, x1.z) VROW(7, x1.w)
#undef VROW
    }
    if (more) {
      __syncthreads();
      STAGE_V(cur ^ 1)
      __syncthreads();
      cur ^= 1;
    }
  }
#undef STAGE_V

  const float LO = -0.99999994f;
  const float SQRT2 = 1.41421356237f;
  const float4 mu4 = *reinterpret_cast<const float4*>(&muv[nBase + tx * 4]);
  const float4 sd4 = *reinterpret_cast<const float4*>(&stdv[nBase + tx * 4]);
  const float mur[4] = {mu4.x, mu4.y, mu4.z, mu4.w};
  const float sdr[4] = {sd4.x, sd4.y, sd4.z, sd4.w};
#pragma unroll
  for (int i = 0; i < 8; ++i) {
    int row = mBase + ty * 8 + i;
    float o0, o1, o2, o3;
#define VOUT(j, dst) { \
      int col = nBase + tx * 4 + j; \
      float m_v = acc[i][j] + mur[j]; \
      uint32_t idx = (uint32_t)row * (uint32_t)N + (uint32_t)col; \
      float f = jax_uniform01(kn0, kn1, idx); \
      float u = fmaxf(LO, fmaf(f, 2.0f, LO)); \
      float nz = SQRT2 * erfinv_xla(u); \
      dst = m_v + nz * sdr[j]; }
    VOUT(0, o0) VOUT(1, o1) VOUT(2, o2) VOUT(3, o3)
#undef VOUT
    float4 s = {o0, o1, o2, o3};
    *reinterpret_cast<float4*>(&Vout[(size_t)row * N + nBase + tx * 4]) = s;
  }
}

extern "C" void kernel_launch(void* const* d_in, const int* in_sizes, int n_in,
                              void* d_out, int out_size, void* d_ws, size_t ws_size,
                              hipStream_t stream) {
  const int B = 4096, V = 3072, NUM_STEPS = 8;
  const float* v_in    = (const float*)d_in[0];
  const float* W       = (const float*)d_in[1];
  const float* b       = (const float*)d_in[2];
  const float* mu      = (const float*)d_in[3];
  const float* log_var = (const float*)d_in[4];
  float* out = (float*)d_out;

  float* invvar = (float*)d_ws;
  float* stdv   = invvar + V;
  uint8_t* h    = (uint8_t*)(stdv + V);   // B*H = 2 MiB

  uint32_t k0a, k0b, kl0, kl1;
  threefry2x32(0u, 42u, 0u, 0u, k0a, k0b);
  threefry2x32(0u, 42u, 0u, 1u, kl0, kl1);
  uint32_t kn0[NUM_STEPS], kn1[NUM_STEPS], kb0[NUM_STEPS], kb1[NUM_STEPS];
  for (int t = 0; t < NUM_STEPS; ++t) {
    uint32_t kt0, kt1;
    threefry2x32(kl0, kl1, 0u, (uint32_t)t, kt0, kt1);
    threefry2x32(kt0, kt1, 0u, 0u, kn0[t], kn1[t]);
    threefry2x32(kt0, kt1, 0u, 1u, kb0[t], kb1[t]);
  }

  prep_kernel<<<(V + 255) / 256, 256, 0, stream>>>(log_var, invvar, stdv, V);

  dim3 gridL(512);                 // (M/64)*(N/64), XCD-swizzled
  dim3 gridV(V / 64, B / 128);     // (48, 32)

  gemm_logit_bern<<<gridL, 256, 0, stream>>>(v_in, W, b, invvar, h, k0a, k0b);

  for (int t = 0; t < NUM_STEPS; ++t) {
    float* vt = out + (size_t)t * B * V;
    gemm_v_sample<<<gridV, 256, 0, stream>>>(h, W, mu, stdv, vt, kn0[t], kn1[t]);
    if (t < NUM_STEPS - 1) {
      gemm_logit_bern<<<gridL, 256, 0, stream>>>(vt, W, b, invvar, h, kb0[t], kb1[t]);
    }
  }
}

// Round 5
// 3324.262 us; speedup vs baseline: 13.4764x; 1.0519x over previous
//
#include <hip/hip_runtime.h>
#include <stdint.h>
#include <stddef.h>

// ---------------------------------------------------------------------------
// GRBM Gibbs sampling, round 5. Exact JAX threefry numerics — every output
// keeps ONE ascending-k fmaf chain -> absmax must stay exactly 0.1015625.
// R4 post-mortem: L stall-bound (VALUBusy 44%, 2 barriers/tile, KT=16 tile
// compute 512cy < 900cy HBM latency). Fix: single-barrier double-buffer
// schedule (STAGE p -> LOAD t+1 -> barrier -> COMPUTE p) in both kernels;
// L moves to KT=32 so per-tile compute (~1024cy) covers HBM latency.
// ---------------------------------------------------------------------------

__host__ __device__ inline void threefry2x32(uint32_t k0, uint32_t k1,
                                             uint32_t x0, uint32_t x1,
                                             uint32_t& o0, uint32_t& o1) {
  uint32_t ks2 = k0 ^ k1 ^ 0x1BD11BDAu;
  x0 += k0; x1 += k1;
#define TFR(r) { x0 += x1; x1 = (x1 << (r)) | (x1 >> (32 - (r))); x1 ^= x0; }
  TFR(13) TFR(15) TFR(26) TFR(6)
  x0 += k1;  x1 += ks2 + 1u;
  TFR(17) TFR(29) TFR(16) TFR(24)
  x0 += ks2; x1 += k0 + 2u;
  TFR(13) TFR(15) TFR(26) TFR(6)
  x0 += k0;  x1 += k1 + 3u;
  TFR(17) TFR(29) TFR(16) TFR(24)
  x0 += k1;  x1 += ks2 + 4u;
  TFR(13) TFR(15) TFR(26) TFR(6)
  x0 += ks2; x1 += k0 + 5u;
#undef TFR
  o0 = x0; o1 = x1;
}

__device__ inline float jax_uniform01(uint32_t key0, uint32_t key1, uint32_t idx) {
  uint32_t o0, o1;
  threefry2x32(key0, key1, 0u, idx, o0, o1);
  uint32_t bits = o0 ^ o1;
  return __uint_as_float((bits >> 9) | 0x3f800000u) - 1.0f;
}

__device__ inline float erfinv_xla(float x) {
  float w = -log1pf(-x * x);
  float p;
  if (w < 5.0f) {
    w = w - 2.5f;
    p = 2.81022636e-08f;
    p = fmaf(p, w, 3.43273939e-07f);
    p = fmaf(p, w, -3.5233877e-06f);
    p = fmaf(p, w, -4.39150654e-06f);
    p = fmaf(p, w, 0.00021858087f);
    p = fmaf(p, w, -0.00125372503f);
    p = fmaf(p, w, -0.00417768164f);
    p = fmaf(p, w, 0.246640727f);
    p = fmaf(p, w, 1.50140941f);
  } else {
    w = sqrtf(w) - 3.0f;
    p = -0.000200214257f;
    p = fmaf(p, w, 0.000100950558f);
    p = fmaf(p, w, 0.00134934322f);
    p = fmaf(p, w, -0.00367342844f);
    p = fmaf(p, w, 0.00573950773f);
    p = fmaf(p, w, -0.0076224613f);
    p = fmaf(p, w, 0.00943887047f);
    p = fmaf(p, w, 1.00167406f);
    p = fmaf(p, w, 2.83297682f);
  }
  return p * x;
}

__global__ void prep_kernel(const float* __restrict__ log_var,
                            float* __restrict__ invvar,
                            float* __restrict__ stdv, int V) {
  int i = blockIdx.x * 256 + threadIdx.x;
  if (i < V) {
    float var = fmaxf(expf(log_var[i]), 1e-8f);
    invvar[i] = 1.0f / var;
    stdv[i] = sqrtf(var);
  }
}

// ---------------------------------------------------------------------------
// Kernel L: logits = (Vin*invvar) @ W + b ; h = bernoulli(sigmoid(logits))
// M=4096, N=512, K=3072. BM=64, BN=64, 256 thr, micro 4x4.
// KT=32, single-barrier dbuf. grid=512, XCD swizzle (xcd = bid&7 owns 8
// row-panels -> Vin read from HBM exactly once, rest L2/L3).
// ---------------------------------------------------------------------------
__global__ __launch_bounds__(256, 1)
void gemm_logit_bern(const float* __restrict__ Vin, const float* __restrict__ Wm,
                     const float* __restrict__ bias, const float* __restrict__ invvar,
                     uint8_t* __restrict__ Hout, uint32_t kb0, uint32_t kb1) {
  const int N = 512, K = 3072;
  const int KT = 32;
  __shared__ float As[2][KT][68];   // [k][m], +4 pad ; 17.4 KB
  __shared__ float Bs[2][KT][64];   // [k][n]        ; 16.4 KB

  const int tid = threadIdx.x;
  const int bid = blockIdx.x;
  const int xcd = bid & 7;
  const int c = bid >> 3;
  const int mb = xcd * 8 + (c >> 3);
  const int nb = c & 7;
  const int mBase = mb * 64, nBase = nb * 64;

  const int tx = tid & 15, ty = tid >> 4;
  const int am = tid >> 2;               // 0..63
  const int ak = (tid & 3) * 4;          // 0,4,8,12  (+16 for hi half)
  const int bk = tid >> 4;               // 0..15     (+16 for hi half)
  const int bn = (tid & 15) * 4;         // 0..60

  float acc[4][4] = {};

  float4 ra0, ra1, riv0, riv1, rb0, rb1;

#define LOADL(t) { \
  int k0 = (t) * KT; \
  ra0  = *reinterpret_cast<const float4*>(&Vin[(size_t)(mBase + am) * K + k0 + ak]); \
  ra1  = *reinterpret_cast<const float4*>(&Vin[(size_t)(mBase + am) * K + k0 + 16 + ak]); \
  riv0 = *reinterpret_cast<const float4*>(&invvar[k0 + ak]); \
  riv1 = *reinterpret_cast<const float4*>(&invvar[k0 + 16 + ak]); \
  rb0  = *reinterpret_cast<const float4*>(&Wm[(size_t)(k0 + bk) * N + nBase + bn]); \
  rb1  = *reinterpret_cast<const float4*>(&Wm[(size_t)(k0 + 16 + bk) * N + nBase + bn]); }

#define STOREL(p) { \
  As[p][ak + 0][am]      = ra0.x * riv0.x; \
  As[p][ak + 1][am]      = ra0.y * riv0.y; \
  As[p][ak + 2][am]      = ra0.z * riv0.z; \
  As[p][ak + 3][am]      = ra0.w * riv0.w; \
  As[p][ak + 16][am]     = ra1.x * riv1.x; \
  As[p][ak + 17][am]     = ra1.y * riv1.y; \
  As[p][ak + 18][am]     = ra1.z * riv1.z; \
  As[p][ak + 19][am]     = ra1.w * riv1.w; \
  *reinterpret_cast<float4*>(&Bs[p][bk][bn])      = rb0; \
  *reinterpret_cast<float4*>(&Bs[p][bk + 16][bn]) = rb1; }

  LOADL(0)

  int p = 0;
  const int NT = K / KT;   // 96
  for (int t = 0; t < NT; ++t) {
    STOREL(p)
    if (t + 1 < NT) LOADL(t + 1)
    __syncthreads();
#pragma unroll
    for (int kk = 0; kk < KT; ++kk) {
      float4 x = *reinterpret_cast<const float4*>(&As[p][kk][ty * 4]);
      float4 y = *reinterpret_cast<const float4*>(&Bs[p][kk][tx * 4]);
#define LROW(i, a) \
      acc[i][0] = fmaf(a, y.x, acc[i][0]); \
      acc[i][1] = fmaf(a, y.y, acc[i][1]); \
      acc[i][2] = fmaf(a, y.z, acc[i][2]); \
      acc[i][3] = fmaf(a, y.w, acc[i][3]);
      LROW(0, x.x) LROW(1, x.y) LROW(2, x.z) LROW(3, x.w)
#undef LROW
    }
    p ^= 1;
  }
#undef LOADL
#undef STOREL

#pragma unroll
  for (int i = 0; i < 4; ++i) {
    int row = mBase + ty * 4 + i;
    uint32_t hp = 0;
#pragma unroll
    for (int j = 0; j < 4; ++j) {
      int col = nBase + tx * 4 + j;
      float logit = acc[i][j] + bias[col];
      float p2 = 0.5f + 0.5f * tanhf(0.5f * logit);
      uint32_t idx = (uint32_t)row * (uint32_t)N + (uint32_t)col;
      float u = jax_uniform01(kb0, kb1, idx);
      hp |= ((u < p2) ? 1u : 0u) << (8 * j);
    }
    *reinterpret_cast<uint32_t*>(&Hout[(size_t)row * N + nBase + tx * 4]) = hp;
  }
}

// ---------------------------------------------------------------------------
// Kernel V: v = h @ W^T + mu + normal*std.  M=4096, N=3072, K=512.
// BM=128, BN=64, 256 thr, micro 8x4. KT=16, single-barrier dbuf.
// grid=(48,32); W col-panels auto-land on one XCD (48 % 8 == 0).
// ---------------------------------------------------------------------------
__global__ __launch_bounds__(256, 2)
void gemm_v_sample(const uint8_t* __restrict__ Hin, const float* __restrict__ Wm,
                   const float* __restrict__ muv, const float* __restrict__ stdv,
                   float* __restrict__ Vout, uint32_t kn0, uint32_t kn1) {
  const int N = 3072, K = 512;
  const int KT = 16;
  __shared__ float As[2][KT][132];   // [k][m 0..127]
  __shared__ float Bs[2][KT][68];    // [k][n 0..63]

  const int tid = threadIdx.x;
  const int mBase = blockIdx.y * 128, nBase = blockIdx.x * 64;
  const int tx = tid & 15, ty = tid >> 4;

  const int am = tid >> 1;               // 0..127
  const int ah = (tid & 1) * 8;          // 0,8
  const int bn = tid >> 2;               // 0..63
  const int bq = (tid & 3) * 4;          // 0,4,8,12

  float acc[8][4] = {};

  uint32_t rh0, rh1;
  float4 rb;

#define LOADV(t) { \
  int k0 = (t) * KT; \
  const uint32_t* hp_ = reinterpret_cast<const uint32_t*>(&Hin[(size_t)(mBase + am) * K + k0 + ah]); \
  rh0 = hp_[0]; rh1 = hp_[1]; \
  rb = *reinterpret_cast<const float4*>(&Wm[(size_t)(nBase + bn) * K + k0 + bq]); }

#define STOREV(p) { \
  As[p][ah + 0][am] = (float)((rh0 >> 0) & 0xffu); \
  As[p][ah + 1][am] = (float)((rh0 >> 8) & 0xffu); \
  As[p][ah + 2][am] = (float)((rh0 >> 16) & 0xffu); \
  As[p][ah + 3][am] = (float)((rh0 >> 24) & 0xffu); \
  As[p][ah + 4][am] = (float)((rh1 >> 0) & 0xffu); \
  As[p][ah + 5][am] = (float)((rh1 >> 8) & 0xffu); \
  As[p][ah + 6][am] = (float)((rh1 >> 16) & 0xffu); \
  As[p][ah + 7][am] = (float)((rh1 >> 24) & 0xffu); \
  Bs[p][bq + 0][bn] = rb.x; \
  Bs[p][bq + 1][bn] = rb.y; \
  Bs[p][bq + 2][bn] = rb.z; \
  Bs[p][bq + 3][bn] = rb.w; }

  LOADV(0)

  int p = 0;
  const int NT = K / KT;   // 32
  for (int t = 0; t < NT; ++t) {
    STOREV(p)
    if (t + 1 < NT) LOADV(t + 1)
    __syncthreads();
#pragma unroll
    for (int kk = 0; kk < KT; ++kk) {
      float4 x0 = *reinterpret_cast<const float4*>(&As[p][kk][ty * 8]);
      float4 x1 = *reinterpret_cast<const float4*>(&As[p][kk][ty * 8 + 4]);
      float4 y  = *reinterpret_cast<const float4*>(&Bs[p][kk][tx * 4]);
#define VROW(i, a) \
      acc[i][0] = fmaf(a, y.x, acc[i][0]); \
      acc[i][1] = fmaf(a, y.y, acc[i][1]); \
      acc[i][2] = fmaf(a, y.z, acc[i][2]); \
      acc[i][3] = fmaf(a, y.w, acc[i][3]);
      VROW(0, x0.x) VROW(1, x0.y) VROW(2, x0.z) VROW(3, x0.w)
      VROW(4, x1.x) VROW(5, x1.y) VROW(6, x1.z) VROW(7, x1.w)
#undef VROW
    }
    p ^= 1;
  }
#undef LOADV
#undef STOREV

  const float LO = -0.99999994f;
  const float SQRT2 = 1.41421356237f;
  const float4 mu4 = *reinterpret_cast<const float4*>(&muv[nBase + tx * 4]);
  const float4 sd4 = *reinterpret_cast<const float4*>(&stdv[nBase + tx * 4]);
  const float mur[4] = {mu4.x, mu4.y, mu4.z, mu4.w};
  const float sdr[4] = {sd4.x, sd4.y, sd4.z, sd4.w};
#pragma unroll
  for (int i = 0; i < 8; ++i) {
    int row = mBase + ty * 8 + i;
    float o0, o1, o2, o3;
#define VOUT(j, dst) { \
      int col = nBase + tx * 4 + j; \
      float m_v = acc[i][j] + mur[j]; \
      uint32_t idx = (uint32_t)row * (uint32_t)N + (uint32_t)col; \
      float f = jax_uniform01(kn0, kn1, idx); \
      float u = fmaxf(LO, fmaf(f, 2.0f, LO)); \
      float nz = SQRT2 * erfinv_xla(u); \
      dst = m_v + nz * sdr[j]; }
    VOUT(0, o0) VOUT(1, o1) VOUT(2, o2) VOUT(3, o3)
#undef VOUT
    float4 s = {o0, o1, o2, o3};
    *reinterpret_cast<float4*>(&Vout[(size_t)row * N + nBase + tx * 4]) = s;
  }
}

extern "C" void kernel_launch(void* const* d_in, const int* in_sizes, int n_in,
                              void* d_out, int out_size, void* d_ws, size_t ws_size,
                              hipStream_t stream) {
  const int B = 4096, V = 3072, NUM_STEPS = 8;
  const float* v_in    = (const float*)d_in[0];
  const float* W       = (const float*)d_in[1];
  const float* b       = (const float*)d_in[2];
  const float* mu      = (const float*)d_in[3];
  const float* log_var = (const float*)d_in[4];
  float* out = (float*)d_out;

  float* invvar = (float*)d_ws;
  float* stdv   = invvar + V;
  uint8_t* h    = (uint8_t*)(stdv + V);   // B*H = 2 MiB

  uint32_t k0a, k0b, kl0, kl1;
  threefry2x32(0u, 42u, 0u, 0u, k0a, k0b);
  threefry2x32(0u, 42u, 0u, 1u, kl0, kl1);
  uint32_t kn0[NUM_STEPS], kn1[NUM_STEPS], kb0[NUM_STEPS], kb1[NUM_STEPS];
  for (int t = 0; t < NUM_STEPS; ++t) {
    uint32_t kt0, kt1;
    threefry2x32(kl0, kl1, 0u, (uint32_t)t, kt0, kt1);
    threefry2x32(kt0, kt1, 0u, 0u, kn0[t], kn1[t]);
    threefry2x32(kt0, kt1, 0u, 1u, kb0[t], kb1[t]);
  }

  prep_kernel<<<(V + 255) / 256, 256, 0, stream>>>(log_var, invvar, stdv, V);

  dim3 gridL(512);                 // (M/64)*(N/64), XCD-swizzled
  dim3 gridV(V / 64, B / 128);     // (48, 32)

  gemm_logit_bern<<<gridL, 256, 0, stream>>>(v_in, W, b, invvar, h, k0a, k0b);

  for (int t = 0; t < NUM_STEPS; ++t) {
    float* vt = out + (size_t)t * B * V;
    gemm_v_sample<<<gridV, 256, 0, stream>>>(h, W, mu, stdv, vt, kn0[t], kn1[t]);
    if (t < NUM_STEPS - 1) {
      gemm_logit_bern<<<gridL, 256, 0, stream>>>(vt, W, b, invvar, h, kb0[t], kb1[t]);
    }
  }
}